// Round 1
// baseline (894.228 us; speedup 1.0000x reference)
//
#include <hip/hip_runtime.h>
#include <hip/hip_fp16.h>

// Problem constants
#define Bc  64
#define Sc  256
#define Icc 256
#define Hh  512
#define HW  1024   // 2*Hh

// swizzle: insert 4 floats of pad per 16 so col-chunk b128 reads spread banks
#define SWZ(h) ((h) + (((h) >> 4) << 2))

__device__ __forceinline__ float fast_tanh(float x) {
  float e = __expf(2.0f * x);
  return 1.0f - 2.0f * __builtin_amdgcn_rcpf(e + 1.0f);
}

template <typename T>
__device__ __forceinline__ float ldf(const T* p) {
  if constexpr (sizeof(T) == 4) return *p;
  else return __half2float(*p);
}
template <typename T>
__device__ __forceinline__ void stf(T* p, float v) {
  if constexpr (sizeof(T) == 4) *p = v;
  else *p = __float2half(v);
}

// ---------------- GEMM: I[m][h] = sum_k X[m][k] * W[h][k] ----------------
// M=16384, N=1024, K=256. 128x64 tile, 256 threads, 8x4 per thread. (unchanged)
template <typename T>
__global__ __launch_bounds__(256, 2) void gemm_xw(const float* __restrict__ X,
                                                  const float* __restrict__ Wm,
                                                  T* __restrict__ Out) {
  __shared__ float As[16][132];  // [k][m], pad 4
  __shared__ float Bs[16][68];   // [k][n], pad 4
  const int tid = threadIdx.x;
  const int m0 = blockIdx.x << 7;   // 128-tile
  const int n0 = blockIdx.y << 6;   // 64-tile
  const int tx4 = (tid & 15) << 2;  // n quad base
  const int ty4 = (tid >> 4) << 2;  // m quad base (0..60)
  const int lr = tid >> 2;          // 0..63 load row
  const int lk = (tid & 3) << 2;    // k quad

  float acc[8][4];
#pragma unroll
  for (int i = 0; i < 8; ++i)
#pragma unroll
    for (int j = 0; j < 4; ++j) acc[i][j] = 0.0f;

  const float* xg0 = X + (size_t)(m0 + lr) * Icc + lk;
  const float* xg1 = X + (size_t)(m0 + 64 + lr) * Icc + lk;
  const float* wg  = Wm + (size_t)(n0 + lr) * Icc + lk;

  for (int k0 = 0; k0 < Icc; k0 += 16) {
    float4 a0 = *(const float4*)(xg0 + k0);
    float4 a1 = *(const float4*)(xg1 + k0);
    float4 bv = *(const float4*)(wg + k0);
    __syncthreads();  // protect previous iter's LDS reads
    As[lk + 0][lr] = a0.x; As[lk + 1][lr] = a0.y;
    As[lk + 2][lr] = a0.z; As[lk + 3][lr] = a0.w;
    As[lk + 0][lr + 64] = a1.x; As[lk + 1][lr + 64] = a1.y;
    As[lk + 2][lr + 64] = a1.z; As[lk + 3][lr + 64] = a1.w;
    Bs[lk + 0][lr] = bv.x; Bs[lk + 1][lr] = bv.y;
    Bs[lk + 2][lr] = bv.z; Bs[lk + 3][lr] = bv.w;
    __syncthreads();
#pragma unroll
    for (int kk = 0; kk < 16; ++kk) {
      float a[8], b[4];
      *(float4*)&a[0] = *(const float4*)&As[kk][ty4];
      *(float4*)&a[4] = *(const float4*)&As[kk][ty4 + 64];
      *(float4*)&b[0] = *(const float4*)&Bs[kk][tx4];
#pragma unroll
      for (int i = 0; i < 8; ++i)
#pragma unroll
        for (int j = 0; j < 4; ++j) acc[i][j] = fmaf(a[i], b[j], acc[i][j]);
    }
  }
#pragma unroll
  for (int i = 0; i < 8; ++i) {
    const int mrow = m0 + ((i < 4) ? (ty4 + i) : (64 + ty4 + i - 4));
    T* op = Out + (size_t)mrow * HW + n0 + tx4;
    if constexpr (sizeof(T) == 4) {
      *(float4*)op = make_float4(acc[i][0], acc[i][1], acc[i][2], acc[i][3]);
    } else {
#pragma unroll
      for (int j = 0; j < 4; ++j) stf(op + j, acc[i][j]);
    }
  }
}

// ---------------- Scan ----------------
// Grid (16, 64): blockIdx.y = batch, blockIdx.x = row-block (32 rows).
// 256 threads remapped: ch = tid&31 (col chunk of 16), g = tid>>5 (row group
// of 4).  A 32-lane half-wave now holds ALL 32 chunk-partials of its 4 rows,
// so the matvec reduction is a 5-step shfl_xor butterfly (no LDS, no barrier)
// and the v-recurrence is computed redundantly per-lane (state in registers).
// One __syncthreads per step (k_s/kt_s double buffer covers the rest).
template <typename T>
__global__ __launch_bounds__(256, 4) void scan_kernel(const T* __restrict__ If,
                                                      float* __restrict__ mem_out,
                                                      float* __restrict__ keys,
                                                      float* __restrict__ vals) {
  const int b = blockIdx.y;
  const int rb = blockIdx.x;
  const int tid = threadIdx.x;
  const int ch = tid & 31;   // col chunk 0..31
  const int g = tid >> 5;    // row group 0..7
  const int r0 = rb << 5;    // first row of block
  const int myrow = r0 + (g << 2);

  __shared__ float k_s[2][640];    // swizzled, double-buffered
  __shared__ float kt_s[2][640];

  constexpr float ALPHA = 0.90483741803595957f;  // exp(-1/10)
  constexpr float DT    = 0.95122942450071400f;  // exp(-1/20)
  constexpr float OMD   = 0.04877057549928599f;  // 1 - DT
  constexpr float LR_   = 0.01f;

  float memreg[64];  // [i*16 + j]: row myrow+i, col ch*16+j
#pragma unroll
  for (int j = 0; j < 64; ++j) memreg[j] = 0.0f;
  float ks0 = 0.f, ks1 = 0.f, tk0 = 0.f, tk1 = 0.f;
  float vs0 = 0.f, vs1 = 0.f, vs2 = 0.f, vs3 = 0.f;
  float vt0 = 0.f, vt1 = 0.f, vt2 = 0.f, vt3 = 0.f;

  const T* ibase = If + (size_t)b * Sc * HW;
  float* keysb = keys + (size_t)b * Sc * Hh;
  float* valsb = vals + (size_t)b * Sc * Hh;

  const int h0 = 2 * tid;            // this thread's two k-chains
  const int sw0 = SWZ(h0);           // sw0+1 == SWZ(h0+1)

  for (int t = 0; t < Sc; ++t) {
    const T* row = ibase + (size_t)t * HW;
    const int buf = t & 1;

    // ---- phase 1: k-channel recurrence (512 chains, 2 per thread) ----
    float ik0, ik1;
    if constexpr (sizeof(T) == 4) {
      float2 v2 = *(const float2*)(row + h0);
      ik0 = v2.x; ik1 = v2.y;
    } else {
      __half2 hv = *(const __half2*)(row + h0);
      float2 v2 = __half22float2(hv);
      ik0 = v2.x; ik1 = v2.y;
    }
    // iv for this thread's 4 rows (redundant across the 32 lanes of a half;
    // L1 broadcast handles it)
    float iv0, iv1, iv2, iv3;
    if constexpr (sizeof(T) == 4) {
      float4 q = *(const float4*)(row + 512 + myrow);
      iv0 = q.x; iv1 = q.y; iv2 = q.z; iv3 = q.w;
    } else {
      __half2 qa = *(const __half2*)(row + 512 + myrow);
      __half2 qb = *(const __half2*)(row + 512 + myrow + 2);
      float2 fa = __half22float2(qa), fb = __half22float2(qb);
      iv0 = fa.x; iv1 = fa.y; iv2 = fb.x; iv3 = fb.y;
    }

    ks0 = ALPHA * ks0 + ik0;
    ks1 = ALPHA * ks1 + ik1;
    float k0 = fast_tanh(ks0);
    float k1 = fast_tanh(ks1);
    tk0 = DT * tk0 + OMD * k0;
    tk1 = DT * tk1 + OMD * k1;
    k_s[buf][sw0] = k0;  k_s[buf][sw0 + 1] = k1;
    kt_s[buf][sw0] = tk0; kt_s[buf][sw0 + 1] = tk1;
    if (rb == 0) {
      *(float2*)&keysb[t * Hh + h0] = make_float2(k0, k1);
    }
    __syncthreads();  // B1 — the only barrier per step

    // ---- phase 2: matvec partials over this thread's 4x16 patch ----
    float p0 = 0.f, p1 = 0.f, p2 = 0.f, p3 = 0.f;
    {
      const float4* kcp = (const float4*)&k_s[buf][ch * 20];
#pragma unroll
      for (int q = 0; q < 4; ++q) {
        const float4 kv = kcp[q];
        const int o = q * 4;
        p0 += memreg[o+0]*kv.x + memreg[o+1]*kv.y + memreg[o+2]*kv.z + memreg[o+3]*kv.w;
        p1 += memreg[16+o+0]*kv.x + memreg[16+o+1]*kv.y + memreg[16+o+2]*kv.z + memreg[16+o+3]*kv.w;
        p2 += memreg[32+o+0]*kv.x + memreg[32+o+1]*kv.y + memreg[32+o+2]*kv.z + memreg[32+o+3]*kv.w;
        p3 += memreg[48+o+0]*kv.x + memreg[48+o+1]*kv.y + memreg[48+o+2]*kv.z + memreg[48+o+3]*kv.w;
      }
    }
    // ---- in-wave butterfly: sum the 32 chunk-partials (mask<32 stays in half)
#pragma unroll
    for (int m = 1; m < 32; m <<= 1) {
      p0 += __shfl_xor(p0, m);
      p1 += __shfl_xor(p1, m);
      p2 += __shfl_xor(p2, m);
      p3 += __shfl_xor(p3, m);
    }

    // ---- phase 3: v-recurrence, redundant per-lane for own 4 rows ----
    float a0, a1, a2, a3, c0, c1, c2, c3;
    {
      vs0 = fmaf(ALPHA, vs0, fmaf(0.2f, p0, iv0));
      vs1 = fmaf(ALPHA, vs1, fmaf(0.2f, p1, iv1));
      vs2 = fmaf(ALPHA, vs2, fmaf(0.2f, p2, iv2));
      vs3 = fmaf(ALPHA, vs3, fmaf(0.2f, p3, iv3));
      float v0 = fast_tanh(vs0);
      float v1 = fast_tanh(vs1);
      float v2 = fast_tanh(vs2);
      float v3 = fast_tanh(vs3);
      vt0 = fmaf(DT, vt0, OMD * v0);
      vt1 = fmaf(DT, vt1, OMD * v1);
      vt2 = fmaf(DT, vt2, OMD * v2);
      vt3 = fmaf(DT, vt3, OMD * v3);
      a0 = fmaf(-LR_ * vt0, vt0, 1.0f);  c0 = LR_ * vt0;
      a1 = fmaf(-LR_ * vt1, vt1, 1.0f);  c1 = LR_ * vt1;
      a2 = fmaf(-LR_ * vt2, vt2, 1.0f);  c2 = LR_ * vt2;
      a3 = fmaf(-LR_ * vt3, vt3, 1.0f);  c3 = LR_ * vt3;
      if (ch == 0) {
        *(float4*)&valsb[t * Hh + myrow] = make_float4(v0, v1, v2, v3);
      }
    }

    // ---- phase 4: rank-1 mem update (a,c local; kt from LDS) ----
    {
      const float4* kt4 = (const float4*)&kt_s[buf][ch * 20];
#pragma unroll
      for (int q = 0; q < 4; ++q) {
        const float4 kv = kt4[q];
        const int o = q * 4;
        memreg[o+0]    = fmaf(memreg[o+0],    a0, c0 * kv.x);
        memreg[o+1]    = fmaf(memreg[o+1],    a0, c0 * kv.y);
        memreg[o+2]    = fmaf(memreg[o+2],    a0, c0 * kv.z);
        memreg[o+3]    = fmaf(memreg[o+3],    a0, c0 * kv.w);
        memreg[16+o+0] = fmaf(memreg[16+o+0], a1, c1 * kv.x);
        memreg[16+o+1] = fmaf(memreg[16+o+1], a1, c1 * kv.y);
        memreg[16+o+2] = fmaf(memreg[16+o+2], a1, c1 * kv.z);
        memreg[16+o+3] = fmaf(memreg[16+o+3], a1, c1 * kv.w);
        memreg[32+o+0] = fmaf(memreg[32+o+0], a2, c2 * kv.x);
        memreg[32+o+1] = fmaf(memreg[32+o+1], a2, c2 * kv.y);
        memreg[32+o+2] = fmaf(memreg[32+o+2], a2, c2 * kv.z);
        memreg[32+o+3] = fmaf(memreg[32+o+3], a2, c2 * kv.w);
        memreg[48+o+0] = fmaf(memreg[48+o+0], a3, c3 * kv.x);
        memreg[48+o+1] = fmaf(memreg[48+o+1], a3, c3 * kv.y);
        memreg[48+o+2] = fmaf(memreg[48+o+2], a3, c3 * kv.z);
        memreg[48+o+3] = fmaf(memreg[48+o+3], a3, c3 * kv.w);
      }
    }
    // no trailing barrier: next step writes the other k_s buffer; its B1
    // (step t+1) separates this step's reads of buf from step t+2's writes.
  }

  // epilogue: write mem (once)
#pragma unroll
  for (int i = 0; i < 4; ++i) {
    float* mb = mem_out + (size_t)b * Hh * Hh +
                (size_t)(myrow + i) * Hh + (ch << 4);
#pragma unroll
    for (int q = 0; q < 4; ++q) {
      *(float4*)(mb + 4 * q) = make_float4(memreg[i*16 + 4*q + 0], memreg[i*16 + 4*q + 1],
                                           memreg[i*16 + 4*q + 2], memreg[i*16 + 4*q + 3]);
    }
  }
}

extern "C" void kernel_launch(void* const* d_in, const int* in_sizes, int n_in,
                              void* d_out, int out_size, void* d_ws, size_t ws_size,
                              hipStream_t stream) {
  const float* x = (const float*)d_in[0];   // (64,256,256) fp32
  const float* W = (const float*)d_in[1];   // (1024,256) fp32
  float* out = (float*)d_out;
  float* mem_out = out;                          // 16,777,216 floats
  float* keys    = out + 16777216;               //  8,388,608 floats
  float* vals    = out + 25165824;               //  8,388,608 floats

  const dim3 gemm_grid(128, 16), gemm_blk(256);
  const dim3 scan_grid(16, 64),  scan_blk(256);
  const size_t i_elems = (size_t)Bc * Sc * HW;   // 16,777,216

  if (ws_size >= i_elems * sizeof(float)) {
    float* If = (float*)d_ws;
    gemm_xw<float><<<gemm_grid, gemm_blk, 0, stream>>>(x, W, If);
    scan_kernel<float><<<scan_grid, scan_blk, 0, stream>>>(If, mem_out, keys, vals);
  } else {
    __half* If = (__half*)d_ws;
    gemm_xw<__half><<<gemm_grid, gemm_blk, 0, stream>>>(x, W, If);
    scan_kernel<__half><<<scan_grid, scan_blk, 0, stream>>>(If, mem_out, keys, vals);
  }
}